// Round 1
// baseline (3584.374 us; speedup 1.0000x reference)
//
#include <hip/hip_runtime.h>
#include <math.h>

#define B_ 4
#define N_ 256
#define L_ 4
#define H_ 256
#define D_ 128
#define DEG_ 16
#define T_ 64

// ws layout (in float units)
#define OFF_H     0          // 262144 floats : h after fc+LN+tanh [B*N, H]
#define OFF_XW    262144     // 524288 floats : xw [B,L,N,D]
#define OFF_FCWT  786432     // 66048  floats : fc_w transposed [258][256]
#define OFF_WHH   852480     // 262144 floats : packed w_hh [256k][256u] float4(i,f,g,o)
#define OFF_WIH   1114624    // 131072 floats : packed w_ih [128k][256u] float4
#define OFF_BIAS  1245696    // 1024 floats   : bias4 [256u] float4
#define OFF_IDX   1246720    // 65536 ints    : neighbor idx [B,L,N,DEG]
// total ~5.25 MB of ws

__device__ __forceinline__ float sigf(float x)  { return 1.f / (1.f + __expf(-x)); }
__device__ __forceinline__ float tanhf_(float x){ return 2.f / (1.f + __expf(-2.f * x)) - 1.f; }

// ---------- prep: transpose fc_w, pack w_hh/w_ih as float4(i,f,g,o), bias ----------
__global__ void k_prep(const float* __restrict__ fc_w, const float* __restrict__ w_ih,
                       const float* __restrict__ w_hh, const float* __restrict__ b_ih,
                       const float* __restrict__ b_hh, float* __restrict__ ws) {
    int i = blockIdx.x * blockDim.x + threadIdx.x;
    const int total = 66048 + 65536 + 32768 + 256;
    for (; i < total; i += gridDim.x * blockDim.x) {
        if (i < 66048) {
            int k = i >> 8, j = i & 255;                 // fcwT[k][j] = fc_w[j][k]
            ws[OFF_FCWT + i] = fc_w[j * 258 + k];
        } else if (i < 66048 + 65536) {
            int p = i - 66048;                           // p = k*256 + t, k<256
            int k = p >> 8, t = p & 255;
            float4 v;
            v.x = w_hh[(t)       * 256 + k];
            v.y = w_hh[(256 + t) * 256 + k];
            v.z = w_hh[(512 + t) * 256 + k];
            v.w = w_hh[(768 + t) * 256 + k];
            ((float4*)(ws + OFF_WHH))[p] = v;
        } else if (i < 66048 + 65536 + 32768) {
            int p = i - (66048 + 65536);                 // p = k*256 + t, k<128
            int k = p >> 8, t = p & 255;
            float4 v;
            v.x = w_ih[(t)       * 128 + k];
            v.y = w_ih[(256 + t) * 128 + k];
            v.z = w_ih[(512 + t) * 128 + k];
            v.w = w_ih[(768 + t) * 128 + k];
            ((float4*)(ws + OFF_WIH))[p] = v;
        } else {
            int t = i - (66048 + 65536 + 32768);
            float4 v;
            v.x = b_ih[t]       + b_hh[t];
            v.y = b_ih[256 + t] + b_hh[256 + t];
            v.z = b_ih[512 + t] + b_hh[512 + t];
            v.w = b_ih[768 + t] + b_hh[768 + t];
            ((float4*)(ws + OFF_BIAS))[t] = v;
        }
    }
}

// ---------- fc + layernorm + tanh : one block per (b,n) row ----------
__global__ void k_fc_ln(const float* __restrict__ x, const float* __restrict__ feat,
                        const float* __restrict__ fc_b, const float* __restrict__ ln_g,
                        const float* __restrict__ ln_b, float* __restrict__ ws) {
    __shared__ float inl[260];
    __shared__ float r1[256], r2[256];
    int row = blockIdx.x, tid = threadIdx.x;
    inl[tid] = x[row * H_ + tid];
    if (tid < 2) inl[H_ + tid] = feat[row * 2 + tid];
    __syncthreads();
    const float* fcwT = ws + OFF_FCWT;
    float acc = fc_b[tid];
    #pragma unroll 4
    for (int k = 0; k < 258; ++k) acc += fcwT[k * 256 + tid] * inl[k];
    r1[tid] = acc; r2[tid] = acc * acc;
    __syncthreads();
    for (int o = 128; o > 0; o >>= 1) {
        if (tid < o) { r1[tid] += r1[tid + o]; r2[tid] += r2[tid + o]; }
        __syncthreads();
    }
    float mu  = r1[0] * (1.f / 256.f);
    float var = r2[0] * (1.f / 256.f) - mu * mu;
    float v = (acc - mu) * rsqrtf(var + 1e-5f) * ln_g[tid] + ln_b[tid];
    ws[OFF_H + row * H_ + tid] = tanhf_(v);
}

// ---------- xw[b,l,n,d] = sum_h h[b,n,h] * W[l,h,d] ----------
__global__ void k_xw(const float* __restrict__ Wm, float* __restrict__ ws) {
    __shared__ float hs[32 * 256];
    int bid = blockIdx.x;                    // ((b*4+l)*8 + tile)
    int tile = bid & 7, l = (bid >> 3) & 3, b = bid >> 5;
    int n0 = tile * 32, tid = threadIdx.x;
    const float* hsrc = ws + OFF_H + (b * N_ + n0) * H_;
    for (int i = tid * 4; i < 32 * 256; i += 256 * 4)
        *(float4*)&hs[i] = *(const float4*)&hsrc[i];
    __syncthreads();
    int r0 = (tid >> 5) * 4, c0 = (tid & 31) * 4;
    float acc[4][4] = {};
    const float* wl = Wm + l * H_ * D_;
    for (int k = 0; k < 256; ++k) {
        float4 wv = *(const float4*)&wl[k * D_ + c0];
        #pragma unroll
        for (int r = 0; r < 4; ++r) {
            float hv = hs[(r0 + r) * 256 + k];
            acc[r][0] += hv * wv.x; acc[r][1] += hv * wv.y;
            acc[r][2] += hv * wv.z; acc[r][3] += hv * wv.w;
        }
    }
    float* xw = ws + OFF_XW;
    #pragma unroll
    for (int r = 0; r < 4; ++r) {
        float4 o; o.x = acc[r][0]; o.y = acc[r][1]; o.z = acc[r][2]; o.w = acc[r][3];
        *(float4*)&xw[((b * L_ + l) * N_ + (n0 + r0 + r)) * D_ + c0] = o;
    }
}

// ---------- neighbor indices: positions of ones in ascending order ----------
__global__ void k_idx(const float* __restrict__ adj, float* __restrict__ ws) {
    int row = blockIdx.x;                    // ((b*4+l)*256 + n)
    int tid = threadIdx.x;
    __shared__ int wc[4];
    bool a = adj[row * N_ + tid] > 0.5f;
    unsigned long long m = __ballot(a);
    int lane = tid & 63, w = tid >> 6;
    if (lane == 0) wc[w] = __popcll(m);
    __syncthreads();
    int base = 0;
    for (int i = 0; i < w; ++i) base += wc[i];
    int pos = base + __popcll(m & ((1ull << lane) - 1ull));
    int* idxb = (int*)(ws + OFF_IDX);
    if (a && pos < DEG_) idxb[row * DEG_ + pos] = tid;
}

// ---------- LSTM over 64 steps, 16 seqs per block, fused epilogue ----------
__global__ __launch_bounds__(256, 1)
void k_lstm(float* __restrict__ out, float* __restrict__ ws) {
    __shared__ float hbuf[16][256];
    __shared__ float xbuf[16][128];
    int tid = threadIdx.x;
    int gs0 = blockIdx.x * 16;              // global seq base; seq = (b*N+n)*L + l
    int b  = gs0 >> 10;
    int n0 = (gs0 >> 2) & 255;
    const float4* whh   = (const float4*)(ws + OFF_WHH);
    const float4* wih   = (const float4*)(ws + OFF_WIH);
    const float4* bias4 = (const float4*)(ws + OFF_BIAS);
    const int*    idxb  = (const int*)(ws + OFF_IDX);
    const float*  xw    = ws + OFF_XW;

    float c[16];
    #pragma unroll
    for (int s = 0; s < 16; ++s) { c[s] = 0.f; hbuf[s][tid] = 0.f; }

    // gather-thread mapping: thread -> (seq ss, dword block d0)
    int ss = tid >> 4, d0 = (tid & 15) * 8;
    int gsq = gs0 + ss;
    int brow = ((gsq >> 10) * L_ + (gsq & 3)) * N_ + ((gsq >> 2) & 255); // (b*4+l)*256+n
    int browBase = brow - ((gsq >> 2) & 255);                            // (b*4+l)*256
    __syncthreads();

    for (int t = 0; t < T_; ++t) {
        if (t < DEG_) {
            int nb = idxb[brow * DEG_ + t];
            const float* src = xw + (browBase + nb) * D_ + d0;
            *(float4*)&xbuf[ss][d0]     = *(const float4*)&src[0];
            *(float4*)&xbuf[ss][d0 + 4] = *(const float4*)&src[4];
        }
        __syncthreads();

        float aI[16] = {}, aF[16] = {}, aG[16] = {}, aO[16] = {};
        #pragma unroll 2
        for (int kc = 0; kc < 64; ++kc) {
            int k = kc * 4;
            float4 w0 = whh[(k + 0) * 256 + tid];
            float4 w1 = whh[(k + 1) * 256 + tid];
            float4 w2 = whh[(k + 2) * 256 + tid];
            float4 w3 = whh[(k + 3) * 256 + tid];
            #pragma unroll
            for (int s = 0; s < 16; ++s) {
                float4 hv = *(const float4*)&hbuf[s][k];
                aI[s] += w0.x * hv.x + w1.x * hv.y + w2.x * hv.z + w3.x * hv.w;
                aF[s] += w0.y * hv.x + w1.y * hv.y + w2.y * hv.z + w3.y * hv.w;
                aG[s] += w0.z * hv.x + w1.z * hv.y + w2.z * hv.z + w3.z * hv.w;
                aO[s] += w0.w * hv.x + w1.w * hv.y + w2.w * hv.z + w3.w * hv.w;
            }
        }
        if (t < DEG_) {
            #pragma unroll 2
            for (int kc = 0; kc < 32; ++kc) {
                int k = kc * 4;
                float4 w0 = wih[(k + 0) * 256 + tid];
                float4 w1 = wih[(k + 1) * 256 + tid];
                float4 w2 = wih[(k + 2) * 256 + tid];
                float4 w3 = wih[(k + 3) * 256 + tid];
                #pragma unroll
                for (int s = 0; s < 16; ++s) {
                    float4 xv = *(const float4*)&xbuf[s][k];
                    aI[s] += w0.x * xv.x + w1.x * xv.y + w2.x * xv.z + w3.x * xv.w;
                    aF[s] += w0.y * xv.x + w1.y * xv.y + w2.y * xv.z + w3.y * xv.w;
                    aG[s] += w0.z * xv.x + w1.z * xv.y + w2.z * xv.z + w3.z * xv.w;
                    aO[s] += w0.w * xv.x + w1.w * xv.y + w2.w * xv.z + w3.w * xv.w;
                }
            }
        }
        __syncthreads();

        float4 bb = bias4[tid];
        #pragma unroll
        for (int s = 0; s < 16; ++s) {
            float gi = sigf(aI[s] + bb.x);
            float gf = sigf(aF[s] + bb.y);
            float gg = tanhf_(aG[s] + bb.z);
            float go = sigf(aO[s] + bb.w);
            c[s] = gf * c[s] + gi * gg;
            hbuf[s][tid] = go * tanhf_(c[s]);
        }
    }
    __syncthreads();

    const float* hln = ws + OFF_H;
    #pragma unroll
    for (int nr = 0; nr < 4; ++nr) {
        float m = 0.25f * (hbuf[nr * 4 + 0][tid] + hbuf[nr * 4 + 1][tid] +
                           hbuf[nr * 4 + 2][tid] + hbuf[nr * 4 + 3][tid]);
        int n = n0 + nr;
        out[(b * N_ + n) * H_ + tid] = 2.f * hln[(b * N_ + n) * H_ + tid] + m;
    }
}

extern "C" void kernel_launch(void* const* d_in, const int* in_sizes, int n_in,
                              void* d_out, int out_size, void* d_ws, size_t ws_size,
                              hipStream_t stream) {
    const float* x    = (const float*)d_in[0];
    const float* feat = (const float*)d_in[1];
    const float* adj  = (const float*)d_in[2];
    const float* fc_w = (const float*)d_in[3];
    const float* fc_b = (const float*)d_in[4];
    const float* ln_g = (const float*)d_in[5];
    const float* ln_b = (const float*)d_in[6];
    const float* Wm   = (const float*)d_in[7];
    const float* w_ih = (const float*)d_in[8];
    const float* w_hh = (const float*)d_in[9];
    const float* b_ih = (const float*)d_in[10];
    const float* b_hh = (const float*)d_in[11];
    float* ws  = (float*)d_ws;
    float* out = (float*)d_out;

    hipLaunchKernelGGL(k_prep,  dim3(160),  dim3(256), 0, stream, fc_w, w_ih, w_hh, b_ih, b_hh, ws);
    hipLaunchKernelGGL(k_fc_ln, dim3(1024), dim3(256), 0, stream, x, feat, fc_b, ln_g, ln_b, ws);
    hipLaunchKernelGGL(k_xw,    dim3(128),  dim3(256), 0, stream, Wm, ws);
    hipLaunchKernelGGL(k_idx,   dim3(4096), dim3(256), 0, stream, adj, ws);
    hipLaunchKernelGGL(k_lstm,  dim3(256),  dim3(256), 0, stream, out, ws);
}

// Round 4
// 1807.584 us; speedup vs baseline: 1.9830x; 1.9830x over previous
//
#include <hip/hip_runtime.h>
#include <hip/hip_bf16.h>
#include <math.h>

#define B_ 4
#define N_ 256
#define L_ 4
#define H_ 256
#define D_ 128
#define DEG_ 16
#define T_ 64

// ws layout (float units) — NOTE: XWB is 524288 bf16 = 262144 floats (R2/R3 bug: was sized 65536)
#define OFF_H     0          // 262144 : h after fc+LN+tanh (f32) [B*N,256]
#define OFF_FCWT  262144     // 66048  : fc_w transposed [258][256]
#define OFF_BIAS  328192     // 1024   : b_ih+b_hh, type-major [4][256]
#define OFF_IDX   329216     // 65536  : neighbor idx (int) [B,L,N,DEG]
#define OFF_XWB   394752     // 262144 : xw bf16 [B,L,N,128]   (ends 656896)
#define OFF_PHH   656896     // 131072 : packed Whh bf16 frags [w=8][nt=8][kt=8][lane=64][8]
#define OFF_PIH   787968     // 65536  : packed Wih bf16 frags [w=8][nt=8][kt=4][lane=64][8]
// total 853504 floats ≈ 3.42 MB

typedef __attribute__((ext_vector_type(8))) short short8;
typedef __attribute__((ext_vector_type(4))) float f32x4;

__device__ __forceinline__ float sigf(float x)  { return 1.f / (1.f + __expf(-x)); }
__device__ __forceinline__ float tanhf_(float x){ return 2.f / (1.f + __expf(-2.f * x)) - 1.f; }
__device__ __forceinline__ unsigned short f2b(float f) {
    __hip_bfloat16 h = __float2bfloat16(f);
    return __builtin_bit_cast(unsigned short, h);
}
__device__ __forceinline__ float b2f(unsigned short s) {
    unsigned int u = ((unsigned int)s) << 16;
    return __builtin_bit_cast(float, u);
}
__device__ __forceinline__ f32x4 splat4(float v) { f32x4 r; r[0]=v; r[1]=v; r[2]=v; r[3]=v; return r; }

// ---------- prep: fc_w transpose + MFMA-fragment weight packing + bias ----------
__global__ void k_prep(const float* __restrict__ fc_w, const float* __restrict__ w_ih,
                       const float* __restrict__ w_hh, const float* __restrict__ b_ih,
                       const float* __restrict__ b_hh, float* __restrict__ ws) {
    int i = blockIdx.x * blockDim.x + threadIdx.x;
    unsigned short* phh = (unsigned short*)(ws + OFF_PHH);
    unsigned short* pih = (unsigned short*)(ws + OFF_PIH);
    if (i < 66048) {
        int k = i >> 8, j = i & 255;
        ws[OFF_FCWT + i] = fc_w[j * 258 + k];
    } else if (i < 66048 + 262144) {
        int p = i - 66048;
        int j = p & 7, lane = (p >> 3) & 63, kt = (p >> 9) & 7, nt = (p >> 12) & 7, w = (p >> 15) & 7;
        int n = (nt >> 1) * 256 + w * 32 + (nt & 1) * 16 + (lane & 15);   // gate row (type*256+unit)
        int k = kt * 32 + (lane >> 4) * 8 + j;
        phh[p] = f2b(w_hh[n * 256 + k]);
    } else if (i < 66048 + 262144 + 131072) {
        int p = i - (66048 + 262144);
        int j = p & 7, lane = (p >> 3) & 63, kt = (p >> 9) & 3, nt = (p >> 11) & 7, w = (p >> 14) & 7;
        int n = (nt >> 1) * 256 + w * 32 + (nt & 1) * 16 + (lane & 15);
        int k = kt * 32 + (lane >> 4) * 8 + j;
        pih[p] = f2b(w_ih[n * 128 + k]);
    } else if (i < 66048 + 262144 + 131072 + 1024) {
        int u = i - (66048 + 262144 + 131072);
        ws[OFF_BIAS + u] = b_ih[u] + b_hh[u];
    }
}

// ---------- fc + layernorm + tanh : one block per (b,n) row ----------
__global__ void k_fc_ln(const float* __restrict__ x, const float* __restrict__ feat,
                        const float* __restrict__ fc_b, const float* __restrict__ ln_g,
                        const float* __restrict__ ln_b, float* __restrict__ ws) {
    __shared__ float inl[260];
    __shared__ float r1[256], r2[256];
    int row = blockIdx.x, tid = threadIdx.x;
    inl[tid] = x[row * H_ + tid];
    if (tid < 2) inl[H_ + tid] = feat[row * 2 + tid];
    __syncthreads();
    const float* fcwT = ws + OFF_FCWT;
    float acc = fc_b[tid];
    #pragma unroll 4
    for (int k = 0; k < 258; ++k) acc += fcwT[k * 256 + tid] * inl[k];
    r1[tid] = acc; r2[tid] = acc * acc;
    __syncthreads();
    for (int o = 128; o > 0; o >>= 1) {
        if (tid < o) { r1[tid] += r1[tid + o]; r2[tid] += r2[tid + o]; }
        __syncthreads();
    }
    float mu  = r1[0] * (1.f / 256.f);
    float var = r2[0] * (1.f / 256.f) - mu * mu;
    float v = (acc - mu) * rsqrtf(var + 1e-5f) * ln_g[tid] + ln_b[tid];
    ws[OFF_H + row * H_ + tid] = tanhf_(v);
}

// ---------- xw[b,l,n,d] = h[b,n,:] @ W[l]  -> bf16 ----------
__global__ void k_xw(const float* __restrict__ Wm, float* __restrict__ ws) {
    __shared__ float hs[32 * 256];
    int bid = blockIdx.x;                    // ((b*4+l)*8 + tile)
    int tile = bid & 7, l = (bid >> 3) & 3, b = bid >> 5;
    int n0 = tile * 32, tid = threadIdx.x;
    const float* hsrc = ws + OFF_H + (b * N_ + n0) * H_;
    for (int i = tid * 4; i < 32 * 256; i += 256 * 4)
        *(float4*)&hs[i] = *(const float4*)&hsrc[i];
    __syncthreads();
    int r0 = (tid >> 5) * 4, c0 = (tid & 31) * 4;
    float acc[4][4] = {};
    const float* wl = Wm + l * H_ * D_;
    for (int k = 0; k < 256; ++k) {
        float4 wv = *(const float4*)&wl[k * D_ + c0];
        #pragma unroll
        for (int r = 0; r < 4; ++r) {
            float hv = hs[(r0 + r) * 256 + k];
            acc[r][0] += hv * wv.x; acc[r][1] += hv * wv.y;
            acc[r][2] += hv * wv.z; acc[r][3] += hv * wv.w;
        }
    }
    unsigned short* xwb = (unsigned short*)(ws + OFF_XWB);
    #pragma unroll
    for (int r = 0; r < 4; ++r) {
        unsigned int lo = (unsigned int)f2b(acc[r][0]) | ((unsigned int)f2b(acc[r][1]) << 16);
        unsigned int hi = (unsigned int)f2b(acc[r][2]) | ((unsigned int)f2b(acc[r][3]) << 16);
        uint2 v; v.x = lo; v.y = hi;
        *(uint2*)&xwb[((b * L_ + l) * N_ + (n0 + r0 + r)) * D_ + c0] = v;
    }
}

// ---------- neighbor indices: positions of ones in ascending order ----------
__global__ void k_idx(const float* __restrict__ adj, float* __restrict__ ws) {
    int row = blockIdx.x;                    // ((b*4+l)*256 + n)
    int tid = threadIdx.x;
    __shared__ int wc[4];
    bool a = adj[row * N_ + tid] > 0.5f;
    unsigned long long m = __ballot(a);
    int lane = tid & 63, w = tid >> 6;
    if (lane == 0) wc[w] = __popcll(m);
    __syncthreads();
    int base = 0;
    for (int i = 0; i < w; ++i) base += wc[i];
    int pos = base + __popcll(m & ((1ull << lane) - 1ull));
    int* idxb = (int*)(ws + OFF_IDX);
    if (a && pos < DEG_) idxb[row * DEG_ + pos] = tid;
}

// ---------- MFMA LSTM: 32 seqs/block, 8 waves, 64 steps, fused epilogue ----------
__global__ __launch_bounds__(512, 2)
void k_lstm(float* __restrict__ out, float* __restrict__ ws) {
    __shared__ __align__(16) unsigned short hbuf[32 * 256];  // swizzled: idx = s*256 + (u ^ ((s&7)<<3))
    __shared__ __align__(16) unsigned short xbuf[32 * 128];  // swizzled likewise (128 cols)
    const int tid = threadIdx.x;
    const int lane = tid & 63, w = tid >> 6;
    const int c15 = lane & 15, lg = lane >> 4;
    const int gs0 = blockIdx.x * 32;

    const short8* ph8 = (const short8*)((const unsigned short*)(ws + OFF_PHH) + w * 32768);
    const short8* pi8 = (const short8*)((const unsigned short*)(ws + OFF_PIH) + w * 16384);
    const float* bias = ws + OFF_BIAS;
    const int* idxb = (const int*)(ws + OFF_IDX);
    const unsigned short* xwb = (const unsigned short*)(ws + OFF_XWB);

    for (int i = tid; i < 32 * 256; i += 512) hbuf[i] = 0;

    // x-staging map: thread -> (seq row ss, 16B part)
    const int ss = tid >> 4, part = tid & 15;
    const int gsq = gs0 + ss;
    const int bb = gsq >> 10, nn = (gsq >> 2) & 255, ll = gsq & 3;
    const int brow = ((bb << 2) + ll) * 256 + nn;
    const int browBase = ((bb << 2) + ll) * 256;
    const int xsto = ss * 16 + (part ^ (ss & 7));

    float bI[2], bF[2], bG[2], bO[2];
    #pragma unroll
    for (int hf = 0; hf < 2; ++hf) {
        int u = w * 32 + hf * 16 + c15;
        bI[hf] = bias[u];       bF[hf] = bias[256 + u];
        bG[hf] = bias[512 + u]; bO[hf] = bias[768 + u];
    }

    float cst[2][2][4];
    #pragma unroll
    for (int m = 0; m < 2; ++m)
        #pragma unroll
        for (int hf = 0; hf < 2; ++hf)
            #pragma unroll
            for (int r = 0; r < 4; ++r) cst[m][hf][r] = 0.f;

    __syncthreads();

    for (int t = 0; t < T_; ++t) {
        if (t < DEG_) {
            int nb = idxb[brow * DEG_ + t];
            const uint4* src = (const uint4*)(xwb + (browBase + nb) * D_);
            ((uint4*)xbuf)[xsto] = src[part];
        }
        short8 bst[2][8];
        #pragma unroll
        for (int kt = 0; kt < 8; ++kt) bst[0][kt] = ph8[kt * 64 + lane];   // prefetch quad 0
        __syncthreads();                                                    // h,x staged

        short8 hA[2][8];
        #pragma unroll
        for (int m = 0; m < 2; ++m)
            #pragma unroll
            for (int kt = 0; kt < 8; ++kt)
                hA[m][kt] = ((const short8*)hbuf)[(m * 16 + c15) * 32 + ((kt * 4 + lg) ^ (c15 & 7))];
        short8 xA[2][4];
        if (t < DEG_) {
            #pragma unroll
            for (int m = 0; m < 2; ++m)
                #pragma unroll
                for (int kt = 0; kt < 4; ++kt)
                    xA[m][kt] = ((const short8*)xbuf)[(m * 16 + c15) * 16 + ((kt * 4 + lg) ^ (c15 & 7))];
        }
        __syncthreads();                                                    // reads done -> safe to overwrite

        f32x4 acc[2][4];
        #pragma unroll
        for (int q = 0; q < 8; ++q) {                  // q = hf*4 + ty
            const int hf = q >> 2, ty = q & 3, nt = ty * 2 + hf;
            if (ty == 0) {
                float bv[4] = {bI[hf], bF[hf], bG[hf], bO[hf]};
                #pragma unroll
                for (int m = 0; m < 2; ++m)
                    #pragma unroll
                    for (int tt = 0; tt < 4; ++tt) acc[m][tt] = splat4(bv[tt]);
            }
            if (q < 7) {                               // prefetch next quad's B frags
                const int nq = q + 1;
                const int nnt = (nq & 3) * 2 + (nq >> 2);
                #pragma unroll
                for (int kt = 0; kt < 8; ++kt) bst[nq & 1][kt] = ph8[(nnt * 8 + kt) * 64 + lane];
            }
            #pragma unroll
            for (int kt = 0; kt < 8; ++kt) {
                acc[0][ty] = __builtin_amdgcn_mfma_f32_16x16x32_bf16(hA[0][kt], bst[q & 1][kt], acc[0][ty], 0, 0, 0);
                acc[1][ty] = __builtin_amdgcn_mfma_f32_16x16x32_bf16(hA[1][kt], bst[q & 1][kt], acc[1][ty], 0, 0, 0);
            }
            if (t < DEG_) {
                short8 bi4[4];
                #pragma unroll
                for (int kt = 0; kt < 4; ++kt) bi4[kt] = pi8[(nt * 4 + kt) * 64 + lane];
                #pragma unroll
                for (int kt = 0; kt < 4; ++kt) {
                    acc[0][ty] = __builtin_amdgcn_mfma_f32_16x16x32_bf16(xA[0][kt], bi4[kt], acc[0][ty], 0, 0, 0);
                    acc[1][ty] = __builtin_amdgcn_mfma_f32_16x16x32_bf16(xA[1][kt], bi4[kt], acc[1][ty], 0, 0, 0);
                }
            }
            if (ty == 3) {                             // all 4 gate types ready for this hf
                #pragma unroll
                for (int m = 0; m < 2; ++m)
                    #pragma unroll
                    for (int r = 0; r < 4; ++r) {
                        float gi = sigf(acc[m][0][r]);
                        float gf = sigf(acc[m][1][r]);
                        float gg = tanhf_(acc[m][2][r]);
                        float go = sigf(acc[m][3][r]);
                        float cc = gf * cst[m][hf][r] + gi * gg;
                        cst[m][hf][r] = cc;
                        float hv = go * tanhf_(cc);
                        int s = m * 16 + lg * 4 + r;
                        hbuf[s * 256 + ((w * 32 + hf * 16 + c15) ^ ((s & 7) << 3))] = f2b(hv);
                    }
            }
        }
    }
    __syncthreads();

    // epilogue: out = 2*h_ln + mean_l h_last
    const float* hln = ws + OFF_H;
    const int p = tid >> 6, u0 = tid & 63;
    const int gpair = blockIdx.x * 8 + p;
    const int ob = gpair >> 8, on = gpair & 255;
    #pragma unroll
    for (int jj = 0; jj < 4; ++jj) {
        int u = u0 + jj * 64;
        float ssum = 0.f;
        #pragma unroll
        for (int l2 = 0; l2 < 4; ++l2) {
            int s = p * 4 + l2;
            ssum += b2f(hbuf[s * 256 + (u ^ ((s & 7) << 3))]);
        }
        int gi = (ob * 256 + on) * 256 + u;
        out[gi] = 2.f * hln[gi] + 0.25f * ssum;
    }
}

extern "C" void kernel_launch(void* const* d_in, const int* in_sizes, int n_in,
                              void* d_out, int out_size, void* d_ws, size_t ws_size,
                              hipStream_t stream) {
    const float* x    = (const float*)d_in[0];
    const float* feat = (const float*)d_in[1];
    const float* adj  = (const float*)d_in[2];
    const float* fc_w = (const float*)d_in[3];
    const float* fc_b = (const float*)d_in[4];
    const float* ln_g = (const float*)d_in[5];
    const float* ln_b = (const float*)d_in[6];
    const float* Wm   = (const float*)d_in[7];
    const float* w_ih = (const float*)d_in[8];
    const float* w_hh = (const float*)d_in[9];
    const float* b_ih = (const float*)d_in[10];
    const float* b_hh = (const float*)d_in[11];
    float* ws  = (float*)d_ws;
    float* out = (float*)d_out;

    hipLaunchKernelGGL(k_prep,  dim3(1798), dim3(256), 0, stream, fc_w, w_ih, w_hh, b_ih, b_hh, ws);
    hipLaunchKernelGGL(k_fc_ln, dim3(1024), dim3(256), 0, stream, x, feat, fc_b, ln_g, ln_b, ws);
    hipLaunchKernelGGL(k_xw,    dim3(128),  dim3(256), 0, stream, Wm, ws);
    hipLaunchKernelGGL(k_idx,   dim3(4096), dim3(256), 0, stream, adj, ws);
    hipLaunchKernelGGL(k_lstm,  dim3(128),  dim3(512), 0, stream, out, ws);
}

// Round 5
// 653.277 us; speedup vs baseline: 5.4868x; 2.7669x over previous
//
#include <hip/hip_runtime.h>
#include <hip/hip_bf16.h>
#include <math.h>

#define B_ 4
#define N_ 256
#define L_ 4
#define H_ 256
#define D_ 128
#define DEG_ 16
#define T_ 64

// ws layout (float units)
#define OFF_H     0          // 262144 : h after fc+LN+tanh (f32) [B*N,256]
#define OFF_FCWT  262144     // 66048  : fc_w transposed [258][256]
#define OFF_BIAS  328192     // 1024   : b_ih+b_hh, type-major [4][256]
#define OFF_IDX   329216     // 65536  : neighbor idx (int) [B,L,N,DEG]
#define OFF_XWB   394752     // 262144 : xw bf16 [B,L,N,128]   (ends 656896)
#define OFF_PHH   656896     // 131072 : packed Whh bf16 frags [slc2][w8][nt4][kt8][lane64][8]
#define OFF_PIH   787968     // 65536  : packed Wih bf16 frags [slc2][w8][nt4][kt4][lane64][8]
#define OFF_HG    853504     // 1048576: h exchange bf16 [128 groups][2 buf][32 rows][256 units]
#define OFF_CTR   1902080    // 256    : per-block step counters (int)
// total 1902336 floats ≈ 7.6 MB

typedef __attribute__((ext_vector_type(8))) short short8;
typedef __attribute__((ext_vector_type(4))) float f32x4;

__device__ __forceinline__ float sigf(float x)  { return 1.f / (1.f + __expf(-x)); }
__device__ __forceinline__ float tanhf_(float x){ return 2.f / (1.f + __expf(-2.f * x)) - 1.f; }
__device__ __forceinline__ unsigned short f2b(float f) {
    __hip_bfloat16 h = __float2bfloat16(f);
    return __builtin_bit_cast(unsigned short, h);
}
__device__ __forceinline__ float b2f(unsigned short s) {
    unsigned int u = ((unsigned int)s) << 16;
    return __builtin_bit_cast(float, u);
}
__device__ __forceinline__ f32x4 splat4(float v) { f32x4 r; r[0]=v; r[1]=v; r[2]=v; r[3]=v; return r; }

// ---------- prep: fc_w transpose + MFMA-fragment weight packing + bias + ctr zero ----------
__global__ void k_prep(const float* __restrict__ fc_w, const float* __restrict__ w_ih,
                       const float* __restrict__ w_hh, const float* __restrict__ b_ih,
                       const float* __restrict__ b_hh, float* __restrict__ ws) {
    int i = blockIdx.x * blockDim.x + threadIdx.x;
    unsigned short* phh = (unsigned short*)(ws + OFF_PHH);
    unsigned short* pih = (unsigned short*)(ws + OFF_PIH);
    if (i < 256) ((int*)(ws + OFF_CTR))[i] = 0;
    if (i < 66048) {
        int k = i >> 8, j = i & 255;
        ws[OFF_FCWT + i] = fc_w[j * 258 + k];
    } else if (i < 66048 + 262144) {
        // phh[slc][w][nt][kt][lane][j]
        int p = i - 66048;
        int j = p & 7, lane = (p >> 3) & 63, kt = (p >> 9) & 7, nt = (p >> 12) & 3, w = (p >> 14) & 7, slc = (p >> 17) & 1;
        int n = nt * 256 + slc * 128 + w * 16 + (lane & 15);
        int k = kt * 32 + (lane >> 4) * 8 + j;
        phh[p] = f2b(w_hh[n * 256 + k]);
    } else if (i < 66048 + 262144 + 131072) {
        // pih[slc][w][nt][kt][lane][j]
        int p = i - (66048 + 262144);
        int j = p & 7, lane = (p >> 3) & 63, kt = (p >> 9) & 3, nt = (p >> 11) & 3, w = (p >> 13) & 7, slc = (p >> 16) & 1;
        int n = nt * 256 + slc * 128 + w * 16 + (lane & 15);
        int k = kt * 32 + (lane >> 4) * 8 + j;
        pih[p] = f2b(w_ih[n * 128 + k]);
    } else if (i < 66048 + 262144 + 131072 + 1024) {
        int u = i - (66048 + 262144 + 131072);
        ws[OFF_BIAS + u] = b_ih[u] + b_hh[u];
    }
}

// ---------- fc + layernorm + tanh : one block per (b,n) row ----------
__global__ void k_fc_ln(const float* __restrict__ x, const float* __restrict__ feat,
                        const float* __restrict__ fc_b, const float* __restrict__ ln_g,
                        const float* __restrict__ ln_b, float* __restrict__ ws) {
    __shared__ float inl[260];
    __shared__ float r1[256], r2[256];
    int row = blockIdx.x, tid = threadIdx.x;
    inl[tid] = x[row * H_ + tid];
    if (tid < 2) inl[H_ + tid] = feat[row * 2 + tid];
    __syncthreads();
    const float* fcwT = ws + OFF_FCWT;
    float acc = fc_b[tid];
    #pragma unroll 4
    for (int k = 0; k < 258; ++k) acc += fcwT[k * 256 + tid] * inl[k];
    r1[tid] = acc; r2[tid] = acc * acc;
    __syncthreads();
    for (int o = 128; o > 0; o >>= 1) {
        if (tid < o) { r1[tid] += r1[tid + o]; r2[tid] += r2[tid + o]; }
        __syncthreads();
    }
    float mu  = r1[0] * (1.f / 256.f);
    float var = r2[0] * (1.f / 256.f) - mu * mu;
    float v = (acc - mu) * rsqrtf(var + 1e-5f) * ln_g[tid] + ln_b[tid];
    ws[OFF_H + row * H_ + tid] = tanhf_(v);
}

// ---------- xw[b,l,n,d] = h[b,n,:] @ W[l]  -> bf16 ----------
__global__ void k_xw(const float* __restrict__ Wm, float* __restrict__ ws) {
    __shared__ float hs[32 * 256];
    int bid = blockIdx.x;                    // ((b*4+l)*8 + tile)
    int tile = bid & 7, l = (bid >> 3) & 3, b = bid >> 5;
    int n0 = tile * 32, tid = threadIdx.x;
    const float* hsrc = ws + OFF_H + (b * N_ + n0) * H_;
    for (int i = tid * 4; i < 32 * 256; i += 256 * 4)
        *(float4*)&hs[i] = *(const float4*)&hsrc[i];
    __syncthreads();
    int r0 = (tid >> 5) * 4, c0 = (tid & 31) * 4;
    float acc[4][4] = {};
    const float* wl = Wm + l * H_ * D_;
    for (int k = 0; k < 256; ++k) {
        float4 wv = *(const float4*)&wl[k * D_ + c0];
        #pragma unroll
        for (int r = 0; r < 4; ++r) {
            float hv = hs[(r0 + r) * 256 + k];
            acc[r][0] += hv * wv.x; acc[r][1] += hv * wv.y;
            acc[r][2] += hv * wv.z; acc[r][3] += hv * wv.w;
        }
    }
    unsigned short* xwb = (unsigned short*)(ws + OFF_XWB);
    #pragma unroll
    for (int r = 0; r < 4; ++r) {
        unsigned int lo = (unsigned int)f2b(acc[r][0]) | ((unsigned int)f2b(acc[r][1]) << 16);
        unsigned int hi = (unsigned int)f2b(acc[r][2]) | ((unsigned int)f2b(acc[r][3]) << 16);
        uint2 v; v.x = lo; v.y = hi;
        *(uint2*)&xwb[((b * L_ + l) * N_ + (n0 + r0 + r)) * D_ + c0] = v;
    }
}

// ---------- neighbor indices: positions of ones in ascending order ----------
__global__ void k_idx(const float* __restrict__ adj, float* __restrict__ ws) {
    int row = blockIdx.x;                    // ((b*4+l)*256 + n)
    int tid = threadIdx.x;
    __shared__ int wc[4];
    bool a = adj[row * N_ + tid] > 0.5f;
    unsigned long long m = __ballot(a);
    int lane = tid & 63, w = tid >> 6;
    if (lane == 0) wc[w] = __popcll(m);
    __syncthreads();
    int base = 0;
    for (int i = 0; i < w; ++i) base += wc[i];
    int pos = base + __popcll(m & ((1ull << lane) - 1ull));
    int* idxb = (int*)(ws + OFF_IDX);
    if (a && pos < DEG_) idxb[row * DEG_ + pos] = tid;
}

// ---------- persistent-weight pairwise LSTM: 256 blocks x 512 thr ----------
// block bid: group g = bid>>1 (32 seqs), slice slc = bid&1 (128 units). Partner = bid^1.
// Wave w owns units slc*128 + w*16 .. +16, all 4 gate types (4 n-frags x 8 k-frags in VGPRs).
__global__ __launch_bounds__(512, 2)
void k_lstm2(float* __restrict__ out, float* __restrict__ ws) {
    __shared__ __align__(16) unsigned short wih_s[65536];    // 128 KB, Wih slice frags
    __shared__ __align__(16) unsigned short hbuf[32 * 256];  // 16 KB, chunk-swizzled h
    const int tid = threadIdx.x;
    const int lane = tid & 63, w = tid >> 6;
    const int c15 = lane & 15, lg = lane >> 4;
    const int bid = blockIdx.x;
    const int g = bid >> 1, slc = bid & 1;
    const int gs0 = g * 32;

    const unsigned short* phh = (const unsigned short*)(ws + OFF_PHH);
    const unsigned short* pih = (const unsigned short*)(ws + OFF_PIH);
    const float* bias = ws + OFF_BIAS;
    const int* idxb = (const int*)(ws + OFF_IDX);
    const unsigned short* xwb = (const unsigned short*)(ws + OFF_XWB);
    unsigned short* hg = (unsigned short*)(ws + OFF_HG);     // [128][2][32][256]
    int* ctr = (int*)(ws + OFF_CTR);

    // Wih slice -> LDS (once)
    {
        const uint4* src = (const uint4*)(pih + slc * 65536);
        uint4* dst = (uint4*)wih_s;
        for (int i = tid; i < 8192; i += 512) dst[i] = src[i];
    }
    // zero hbuf
    for (int i = tid; i < 4096; i += 512) ((unsigned int*)hbuf)[i] = 0;

    // persistent Whh fragments (loaded once)
    short8 WH[4][8];
    const short8* ph8 = (const short8*)phh;
    #pragma unroll
    for (int nt = 0; nt < 4; ++nt)
        #pragma unroll
        for (int kt = 0; kt < 8; ++kt)
            WH[nt][kt] = ph8[(((slc * 8 + w) * 32) + nt * 8 + kt) * 64 + lane];

    float bb4[4];
    #pragma unroll
    for (int nt = 0; nt < 4; ++nt) bb4[nt] = bias[nt * 256 + slc * 128 + w * 16 + c15];

    // x source rows per m (lane's A-row = seq gs0 + m*16 + c15)
    int xrow[2], xbb[2];
    #pragma unroll
    for (int m = 0; m < 2; ++m) {
        int gsq = gs0 + m * 16 + c15;
        int bbx = gsq >> 10, nn = (gsq >> 2) & 255, ll = gsq & 3;
        xbb[m] = ((bbx << 2) + ll) * 256;
        xrow[m] = xbb[m] + nn;
    }

    float cst[2][4];
    #pragma unroll
    for (int m = 0; m < 2; ++m)
        #pragma unroll
        for (int r = 0; r < 4; ++r) cst[m][r] = 0.f;

    // staging/export map: thread -> (row sr, 8-u16 chunk sch) of a 128-unit half
    const int sr = tid >> 4, sch = tid & 15;
    const int slcP = 1 - slc;

    __syncthreads();

    for (int t = 0; t < T_; ++t) {
        const int cur = t & 1, nxt = cur ^ 1;
        if (t > 0) {
            if (tid == 0) {
                while (__hip_atomic_load(ctr + (bid ^ 1), __ATOMIC_ACQUIRE, __HIP_MEMORY_SCOPE_AGENT) < t)
                    __builtin_amdgcn_s_sleep(2);
            }
            __syncthreads();
            // stage partner's half of h_t into LDS (swizzled chunks)
            {
                const unsigned long long* src = (const unsigned long long*)
                    (hg + ((long)(g * 2 + cur) * 32 + sr) * 256 + slcP * 128 + sch * 8);
                unsigned long long v0 = __hip_atomic_load(src,     __ATOMIC_RELAXED, __HIP_MEMORY_SCOPE_AGENT);
                unsigned long long v1 = __hip_atomic_load(src + 1, __ATOMIC_RELAXED, __HIP_MEMORY_SCOPE_AGENT);
                unsigned short* d = hbuf + sr * 256 + (((slcP * 16 + sch) ^ (sr & 7)) * 8);
                *(unsigned long long*)d = v0;
                *(unsigned long long*)(d + 4) = v1;
            }
            __syncthreads();
        }

        float hv[2][4];
        #pragma unroll
        for (int m = 0; m < 2; ++m) {
            short8 hA[8];
            #pragma unroll
            for (int kt = 0; kt < 8; ++kt)
                hA[kt] = *(const short8*)&hbuf[(m * 16 + c15) * 256 + (((kt * 4 + lg) ^ (c15 & 7)) * 8)];
            short8 xA[4];
            if (t < DEG_) {
                int nb = idxb[xrow[m] * DEG_ + t];
                const short8* s8 = (const short8*)(xwb + (xbb[m] + nb) * D_);
                #pragma unroll
                for (int kt = 0; kt < 4; ++kt) xA[kt] = s8[kt * 4 + lg];
            }
            f32x4 acc[4];
            #pragma unroll
            for (int nt = 0; nt < 4; ++nt) {
                acc[nt] = splat4(bb4[nt]);
                #pragma unroll
                for (int kt = 0; kt < 8; ++kt)
                    acc[nt] = __builtin_amdgcn_mfma_f32_16x16x32_bf16(hA[kt], WH[nt][kt], acc[nt], 0, 0, 0);
                if (t < DEG_) {
                    #pragma unroll
                    for (int kt = 0; kt < 4; ++kt) {
                        short8 wf = *(const short8*)&wih_s[(((w * 4 + nt) * 4 + kt) * 64 + lane) * 8];
                        acc[nt] = __builtin_amdgcn_mfma_f32_16x16x32_bf16(xA[kt], wf, acc[nt], 0, 0, 0);
                    }
                }
            }
            #pragma unroll
            for (int r = 0; r < 4; ++r) {
                float gi = sigf(acc[0][r]);
                float gf = sigf(acc[1][r]);
                float gg = tanhf_(acc[2][r]);
                float go = sigf(acc[3][r]);
                float cc = gf * cst[m][r] + gi * gg;
                cst[m][r] = cc;
                hv[m][r] = go * tanhf_(cc);
            }
        }
        __syncthreads();   // all hbuf reads of h_t complete
        // write own h_{t+1} into hbuf (own unit columns)
        #pragma unroll
        for (int m = 0; m < 2; ++m)
            #pragma unroll
            for (int r = 0; r < 4; ++r) {
                int row = m * 16 + lg * 4 + r;
                int cu = slc * 128 + w * 16 + c15;
                int chunk = (cu >> 3) ^ (row & 7);
                hbuf[row * 256 + chunk * 8 + (c15 & 7)] = f2b(hv[m][r]);
            }
        __syncthreads();   // own half complete in LDS
        if (t < T_ - 1) {
            // export own half -> hg[nxt]; publish step counter
            const unsigned short* s = hbuf + sr * 256 + (((slc * 16 + sch) ^ (sr & 7)) * 8);
            unsigned long long v0 = *(const unsigned long long*)s;
            unsigned long long v1 = *(const unsigned long long*)(s + 4);
            unsigned long long* d = (unsigned long long*)
                (hg + ((long)(g * 2 + nxt) * 32 + sr) * 256 + slc * 128 + sch * 8);
            __hip_atomic_store(d,     v0, __ATOMIC_RELAXED, __HIP_MEMORY_SCOPE_AGENT);
            __hip_atomic_store(d + 1, v1, __ATOMIC_RELAXED, __HIP_MEMORY_SCOPE_AGENT);
            __syncthreads();   // drains stores (vmcnt 0) block-wide
            if (tid == 0)
                __hip_atomic_store(ctr + bid, t + 1, __ATOMIC_RELEASE, __HIP_MEMORY_SCOPE_AGENT);
        }
    }

    // epilogue: out = 2*h_ln + mean_l h_last over this block's 128 units
    const float* hln = ws + OFF_H;
    const int p = tid >> 6, uu = tid & 63;
    const int bn = g * 8 + p;
    #pragma unroll
    for (int j = 0; j < 2; ++j) {
        int cu = slc * 128 + j * 64 + uu;
        float ssum = 0.f;
        #pragma unroll
        for (int l2 = 0; l2 < 4; ++l2) {
            int s = p * 4 + l2;
            ssum += b2f(hbuf[s * 256 + (((cu >> 3) ^ (s & 7)) * 8) + (cu & 7)]);
        }
        int gi = bn * 256 + cu;
        out[gi] = 2.f * hln[gi] + 0.25f * ssum;
    }
}

extern "C" void kernel_launch(void* const* d_in, const int* in_sizes, int n_in,
                              void* d_out, int out_size, void* d_ws, size_t ws_size,
                              hipStream_t stream) {
    const float* x    = (const float*)d_in[0];
    const float* feat = (const float*)d_in[1];
    const float* adj  = (const float*)d_in[2];
    const float* fc_w = (const float*)d_in[3];
    const float* fc_b = (const float*)d_in[4];
    const float* ln_g = (const float*)d_in[5];
    const float* ln_b = (const float*)d_in[6];
    const float* Wm   = (const float*)d_in[7];
    const float* w_ih = (const float*)d_in[8];
    const float* w_hh = (const float*)d_in[9];
    const float* b_ih = (const float*)d_in[10];
    const float* b_hh = (const float*)d_in[11];
    float* ws  = (float*)d_ws;
    float* out = (float*)d_out;

    hipLaunchKernelGGL(k_prep,   dim3(1798), dim3(256), 0, stream, fc_w, w_ih, w_hh, b_ih, b_hh, ws);
    hipLaunchKernelGGL(k_fc_ln,  dim3(1024), dim3(256), 0, stream, x, feat, fc_b, ln_g, ln_b, ws);
    hipLaunchKernelGGL(k_xw,     dim3(128),  dim3(256), 0, stream, Wm, ws);
    hipLaunchKernelGGL(k_idx,    dim3(4096), dim3(256), 0, stream, adj, ws);
    hipLaunchKernelGGL(k_lstm2,  dim3(256),  dim3(512), 0, stream, out, ws);
}